// Round 1
// baseline (2625.588 us; speedup 1.0000x reference)
//
#include <hip/hip_runtime.h>
#include <stdint.h>

#define F_DIM 2048
#define H_DIM 4096
#define E_NUM 8
#define B_TOK 8192    // G*S tokens
#define T_ROWS 16384  // B_TOK * top_k
#define T_PAD  16512  // +128 pad rows (stage loads clamp to T_PAD-1)
#define NMB_MAX 72    // max 256-row M-blocks (bound: 64 + 7)
#define BK 64
#define BM 256
#define BN 256

typedef __attribute__((ext_vector_type(8))) short bf16x8;   // 8 bf16 (4 VGPRs)
typedef __attribute__((ext_vector_type(4))) float f32x4;    // 4 fp32 acc

// ---------- helpers ----------
__device__ __forceinline__ unsigned short f2bf(float f) {
  union { float f; unsigned u; } v; v.f = f;
  unsigned u = v.u;
  unsigned r = u + 0x7fffu + ((u >> 16) & 1u);   // RNE
  return (unsigned short)(r >> 16);
}
__device__ __forceinline__ float bf2f(unsigned short u) {
  union { unsigned u; float f; } v; v.u = ((unsigned)u) << 16;
  return v.f;
}
__device__ __forceinline__ float gelu_tanh(float x) {
  float z = 0.7978845608028654f * (x + 0.044715f * x * x * x);
  float t = 1.0f - 2.0f / (__expf(2.0f * z) + 1.0f);
  return 0.5f * x * (1.0f + t);
}
__device__ __forceinline__ void gload16(const void* g, void* l) {
  __builtin_amdgcn_global_load_lds(
      (const __attribute__((address_space(1))) void*)g,
      (__attribute__((address_space(3))) void*)l, 16, 0, 0);
}

// ---------- 1. fp32 -> bf16 elementwise (w_gating) ----------
__global__ __launch_bounds__(256) void k_convert(const float* __restrict__ src,
                                                 unsigned short* __restrict__ dst,
                                                 long n4) {
  long i = (long)blockIdx.x * blockDim.x + threadIdx.x;
  long stride = (long)gridDim.x * blockDim.x;
  for (; i < n4; i += stride) {
    float4 v = ((const float4*)src)[i];
    ushort4 o;
    o.x = f2bf(v.x); o.y = f2bf(v.y); o.z = f2bf(v.z); o.w = f2bf(v.w);
    ((ushort4*)dst)[i] = o;
  }
}

// ---------- 2. router: RMSnorm -> logits -> softmax top-2 ----------
// x row loaded ONCE into registers (8 floats/thread), reused for both the
// sum-of-squares and the logit pass.
__global__ __launch_bounds__(256) void k_router(const float* __restrict__ x,
                                                const float* __restrict__ wr,
                                                const float* __restrict__ rscale,
                                                const float* __restrict__ pes,
                                                int* __restrict__ counts,
                                                int* __restrict__ meta_e,
                                                float* __restrict__ meta_w) {
  int t = blockIdx.x;
  int tid = threadIdx.x;
  const float4* x4 = (const float4*)(x + (long)t * F_DIM);
  float4 v0 = x4[tid], v1 = x4[tid + 256];
  const float4* s4 = (const float4*)rscale;
  float4 s0 = s4[tid], s1 = s4[tid + 256];

  __shared__ float red[4];
  __shared__ float lg[4][8];

  float ss = v0.x * v0.x + v0.y * v0.y + v0.z * v0.z + v0.w * v0.w +
             v1.x * v1.x + v1.y * v1.y + v1.z * v1.z + v1.w * v1.w;
  for (int o = 32; o >= 1; o >>= 1) ss += __shfl_down(ss, o, 64);
  if ((tid & 63) == 0) red[tid >> 6] = ss;
  __syncthreads();
  float sumsq = red[0] + red[1] + red[2] + red[3];
  float scale = rsqrtf(sumsq * (1.0f / F_DIM) + 1e-6f) * rsqrtf((float)F_DIM);

  float acc[8];
#pragma unroll
  for (int e = 0; e < 8; e++) acc[e] = 0.f;
#pragma unroll
  for (int j = 0; j < 4; j++) {
    float u = ((const float*)&v0)[j] * ((const float*)&s0)[j];
    const float4* wrow = (const float4*)(wr + (long)(4 * tid + j) * 8);
    float4 wa = wrow[0], wb = wrow[1];
    acc[0] += u * wa.x; acc[1] += u * wa.y; acc[2] += u * wa.z; acc[3] += u * wa.w;
    acc[4] += u * wb.x; acc[5] += u * wb.y; acc[6] += u * wb.z; acc[7] += u * wb.w;
  }
#pragma unroll
  for (int j = 0; j < 4; j++) {
    float u = ((const float*)&v1)[j] * ((const float*)&s1)[j];
    const float4* wrow = (const float4*)(wr + (long)(4 * (tid + 256) + j) * 8);
    float4 wa = wrow[0], wb = wrow[1];
    acc[0] += u * wa.x; acc[1] += u * wa.y; acc[2] += u * wa.z; acc[3] += u * wa.w;
    acc[4] += u * wb.x; acc[5] += u * wb.y; acc[6] += u * wb.z; acc[7] += u * wb.w;
  }
#pragma unroll
  for (int e = 0; e < 8; e++) {
    float a = acc[e];
    for (int o = 32; o >= 1; o >>= 1) a += __shfl_down(a, o, 64);
    if ((tid & 63) == 0) lg[tid >> 6][e] = a;
  }
  __syncthreads();
  if (tid == 0) {
    float l[8];
#pragma unroll
    for (int e = 0; e < 8; e++)
      l[e] = (lg[0][e] + lg[1][e] + lg[2][e] + lg[3][e]) * scale;
    int e0 = 0;
    for (int e = 1; e < 8; e++) if (l[e] > l[e0]) e0 = e;
    int e1 = (e0 == 0) ? 1 : 0;
    for (int e = 0; e < 8; e++) if (e != e0 && l[e] > l[e1]) e1 = e;
    float p1 = __expf(l[e1] - l[e0]);
    float inv = 1.0f / (1.0f + p1);
    meta_e[2 * t] = e0; meta_e[2 * t + 1] = e1;
    meta_w[2 * t] = inv * pes[e0];
    meta_w[2 * t + 1] = p1 * inv * pes[e1];
    atomicAdd(&counts[e0], 1);
    atomicAdd(&counts[e1], 1);
  }
}

// ---------- 3. prefix sum + M-block schedule (256-row blocks) ----------
__global__ void k_sched(const int* __restrict__ counts, int* __restrict__ segoff,
                        int* __restrict__ nblocks, int4* __restrict__ sched) {
  if (threadIdx.x == 0 && blockIdx.x == 0) {
    int off = 0, nb = 0;
    for (int e = 0; e < 8; e++) {
      segoff[e] = off;
      int c = counts[e];
      int end = off + c;
      for (int i = 0; i < c; i += BM) {
        sched[nb].x = off + i; sched[nb].y = end; sched[nb].z = e; nb++;
      }
      off = end;
    }
    segoff[8] = off;
    *nblocks = nb;
    for (int b = nb; b < NMB_MAX; b++) { sched[b].x = 0; sched[b].y = 0; sched[b].z = 0; }
  }
}

// ---------- 4. scatter: assign sorted positions ----------
__global__ __launch_bounds__(256) void k_scatter(const int* __restrict__ meta_e,
                                                 const int* __restrict__ segoff,
                                                 int* __restrict__ fills,
                                                 int* __restrict__ meta_pos,
                                                 int* __restrict__ tok_of_row) {
  int t = blockIdx.x * blockDim.x + threadIdx.x;
  if (t >= B_TOK) return;
#pragma unroll
  for (int s = 0; s < 2; s++) {
    int e = meta_e[2 * t + s];
    int pos = segoff[e] + atomicAdd(&fills[e], 1);
    meta_pos[2 * t + s] = pos;
    tok_of_row[pos] = t;
  }
}

// ---------- 5. gather x rows -> bf16 sorted_x (+zero pad rows) ----------
__global__ __launch_bounds__(256) void k_gather(const float* __restrict__ x,
                                                const int* __restrict__ tok_of_row,
                                                unsigned short* __restrict__ sx) {
  int r = blockIdx.x;
  int tid = threadIdx.x;
  unsigned short* dst = sx + (long)r * F_DIM;
  if (r < T_ROWS) {
    const float4* src = (const float4*)(x + (long)tok_of_row[r] * F_DIM);
    for (int i = tid; i < F_DIM / 4; i += 256) {
      float4 v = src[i];
      ushort4 o;
      o.x = f2bf(v.x); o.y = f2bf(v.y); o.z = f2bf(v.z); o.w = f2bf(v.w);
      ((ushort4*)dst)[i] = o;
    }
  } else {
    ushort4 z = make_ushort4(0, 0, 0, 0);
    for (int i = tid; i < F_DIM / 4; i += 256) ((ushort4*)dst)[i] = z;
  }
}

// ================= 256x256 8-phase GEMM machinery =================
// LDS granule XOR-swizzle: 16B granule g of row r stored at position g^(r&7).
// Staged via linear global_load_lds with pre-swizzled per-lane global source
// (rule #21: swizzle BOTH source and read sides, LDS dest linear).
// Per K-tile: 4 phases, each {ds_read quadrant; barrier; lgkmcnt(0);
// sched_barrier; setprio(1); 16 MFMA; setprio(0); barrier}.
// Next K-tile fully staged at iteration top; counted vmcnt(8) (never 0 in
// the main loop) keeps 8 loads/thread in flight across the phase barriers.

#define DSA(MH) \
  _Pragma("unroll") for (int mt = 0; mt < 4; mt++) \
  _Pragma("unroll") for (int ks = 0; ks < 2; ks++) { \
    int r_ = wm * 128 + (MH) * 64 + mt * 16 + lrow; \
    aR[mt * 2 + ks] = *(const bf16x8*)&sA[cur][r_ * BK + ((((ks << 2) + q) ^ (r_ & 7)) << 3)]; \
  }

#define DSB(NH) \
  _Pragma("unroll") for (int nt = 0; nt < 2; nt++) \
  _Pragma("unroll") for (int ks = 0; ks < 2; ks++) { \
    int r_ = wn * 64 + (NH) * 32 + nt * 16 + lrow; \
    bR[nt * 2 + ks] = *(const bf16x8*)&sB[cur][r_ * BK + ((((ks << 2) + q) ^ (r_ & 7)) << 3)]; \
  }

#define MMA(MH, NH) \
  _Pragma("unroll") for (int mt = 0; mt < 4; mt++) \
  _Pragma("unroll") for (int nt = 0; nt < 2; nt++) \
  _Pragma("unroll") for (int ks = 0; ks < 2; ks++) \
    acc[(MH) * 4 + mt][(NH) * 2 + nt] = __builtin_amdgcn_mfma_f32_16x16x32_bf16( \
        aR[mt * 2 + ks], bR[nt * 2 + ks], acc[(MH) * 4 + mt][(NH) * 2 + nt], 0, 0, 0);

#define PHASE_PRE \
  asm volatile("s_barrier" ::: "memory"); \
  asm volatile("s_waitcnt lgkmcnt(0)" ::: "memory"); \
  __builtin_amdgcn_sched_barrier(0); \
  __builtin_amdgcn_s_setprio(1);

#define PHASE_POST \
  __builtin_amdgcn_s_setprio(0); \
  __builtin_amdgcn_sched_barrier(0); \
  asm volatile("s_barrier" ::: "memory");

#define ITER_TOP(VMC) \
  asm volatile("s_waitcnt vmcnt(" #VMC ")" ::: "memory"); \
  __builtin_amdgcn_sched_barrier(0); \
  asm volatile("s_barrier" ::: "memory"); \
  __builtin_amdgcn_sched_barrier(0);

// ---------- 6. GEMM1: sorted_x @ w_gate, fused gelu(g0)*g1 ----------
// N-tile = 128 h-cols x {gate0, gate1} interleaved at 16-col fragment
// granularity: tile B-row n -> matrix g=(n>>4)&1, h-row=(n>>5)*16+(n&15).
// Each wave thus owns BOTH gates of its h columns -> gelu fuses in-register.
__global__ __launch_bounds__(512, 2) void k_gemm_gate(
    const unsigned short* __restrict__ sx,  // [T_PAD][F]
    const unsigned short* __restrict__ wg,  // [E][2H][F]  (B^T layout)
    const int4* __restrict__ sched, const int* __restrict__ nblocks,
    unsigned short* __restrict__ act)       // [T_PAD][H]
{
  int mb = blockIdx.y;
  if (mb >= *nblocks) return;
  int4 sc = sched[mb];
  int row0 = sc.x, row_end = sc.y, e = sc.z;
  int h0 = blockIdx.x * 128;

  __shared__ __align__(16) unsigned short sA[2][BM * BK];  // 64 KiB
  __shared__ __align__(16) unsigned short sB[2][BM * BK];  // 64 KiB

  int tid = threadIdx.x, lane = tid & 63, w = tid >> 6;
  int wm = w >> 2, wn = w & 3;            // 2 (M) x 4 (N) waves
  int lrow = lane & 15, q = lane >> 4;
  int srow8 = lane >> 3;                  // row within 8-row chunk
  int scol = ((lane & 7) ^ srow8) << 3;   // swizzled global granule (elements)

  const unsigned short* B0 = wg + ((long)e * 2 * H_DIM + h0) * F_DIM;
  const unsigned short* B1 = wg + ((long)e * 2 * H_DIM + H_DIM + h0) * F_DIM;

  f32x4 acc[8][4];
  f32x4 z4 = {0.f, 0.f, 0.f, 0.f};
#pragma unroll
  for (int i_ = 0; i_ < 8; i_++)
#pragma unroll
    for (int j_ = 0; j_ < 4; j_++) acc[i_][j_] = z4;
  bf16x8 aR[8], bR[4];

#define STAGE_G1(T) { \
    int k0_ = (T) * BK; \
    unsigned short* dA = &sA[(T) & 1][0]; \
    unsigned short* dB = &sB[(T) & 1][0]; \
    _Pragma("unroll") for (int i = 0; i < 4; i++) { \
      int c = w * 4 + i; \
      int rA_ = row0 + 8 * c + srow8; rA_ = rA_ < T_PAD - 1 ? rA_ : T_PAD - 1; \
      gload16(sx + (long)rA_ * F_DIM + k0_ + scol, (char*)dA + c * 1024 + lane * 16); \
      int rB_ = 8 * c + srow8; \
      const unsigned short* bb = (((c >> 1) & 1) ? B1 : B0); \
      int hr_ = ((rB_ >> 5) << 4) + (rB_ & 15); \
      gload16(bb + (long)hr_ * F_DIM + k0_ + scol, (char*)dB + c * 1024 + lane * 16); \
    } }

  const int NT = F_DIM / BK;  // 32
  STAGE_G1(0);
  for (int t = 0; t < NT; ++t) {
    int cur = t & 1;
    if (t + 1 < NT) {
      STAGE_G1(t + 1);
      ITER_TOP(8)
    } else {
      ITER_TOP(0)
    }
    DSA(0); DSB(0); PHASE_PRE; MMA(0, 0); PHASE_POST;
    DSB(1);         PHASE_PRE; MMA(0, 1); PHASE_POST;
    DSA(1);         PHASE_PRE; MMA(1, 1); PHASE_POST;
    DSB(0);         PHASE_PRE; MMA(1, 0); PHASE_POST;
  }
#undef STAGE_G1

  int lr4 = q * 4;
#pragma unroll
  for (int mt = 0; mt < 8; mt++) {
#pragma unroll
    for (int hf = 0; hf < 2; hf++) {
      f32x4 g0 = acc[mt][hf * 2], g1 = acc[mt][hf * 2 + 1];
      int h = h0 + (wn * 2 + hf) * 16 + lrow;
      long mbase = row0 + wm * 128 + mt * 16 + lr4;
#pragma unroll
      for (int r = 0; r < 4; r++) {
        long m = mbase + r;
        if (m < row_end)
          act[m * H_DIM + h] = f2bf(gelu_tanh(g0[r]) * g1[r]);
      }
    }
  }
}

// ---------- 7. transpose w_linear (E,H,F) fp32 -> (E,F,H) bf16 ----------
__global__ __launch_bounds__(256) void k_transpose(const float* __restrict__ wl,
                                                   unsigned short* __restrict__ wlt) {
  __shared__ float t[64 * 65];
  int e = blockIdx.z;
  int h0 = blockIdx.y * 64, f0 = blockIdx.x * 64;
  int tx = threadIdx.x & 63, ty = threadIdx.x >> 6;  // (64,4)
  const float* src = wl + ((long)e * H_DIM + h0) * F_DIM + f0;
#pragma unroll
  for (int r = 0; r < 16; r++) {
    int hl = r * 4 + ty;
    t[hl * 65 + tx] = src[(long)hl * F_DIM + tx];
  }
  __syncthreads();
  unsigned short* dst = wlt + ((long)e * F_DIM + f0) * H_DIM + h0;
#pragma unroll
  for (int r = 0; r < 16; r++) {
    int fl = r * 4 + ty;
    dst[(long)fl * H_DIM + tx] = f2bf(t[tx * 65 + fl]);
  }
}

// ---------- 8. GEMM2: act @ w_linear^T -> eout ----------
__global__ __launch_bounds__(512, 2) void k_gemm_out(
    const unsigned short* __restrict__ act,  // [T_PAD][H]
    const unsigned short* __restrict__ wlt,  // [E][F][H]  (B^T layout)
    const int4* __restrict__ sched, const int* __restrict__ nblocks,
    unsigned short* __restrict__ eout)       // [T_ROWS][F]
{
  int mb = blockIdx.y;
  if (mb >= *nblocks) return;
  int4 sc = sched[mb];
  int row0 = sc.x, row_end = sc.y, e = sc.z;
  int n0 = blockIdx.x * BN;

  __shared__ __align__(16) unsigned short sA[2][BM * BK];
  __shared__ __align__(16) unsigned short sB[2][BM * BK];

  int tid = threadIdx.x, lane = tid & 63, w = tid >> 6;
  int wm = w >> 2, wn = w & 3;
  int lrow = lane & 15, q = lane >> 4;
  int srow8 = lane >> 3;
  int scol = ((lane & 7) ^ srow8) << 3;

  const unsigned short* Bb = wlt + ((long)e * F_DIM + n0) * H_DIM;

  f32x4 acc[8][4];
  f32x4 z4 = {0.f, 0.f, 0.f, 0.f};
#pragma unroll
  for (int i_ = 0; i_ < 8; i_++)
#pragma unroll
    for (int j_ = 0; j_ < 4; j_++) acc[i_][j_] = z4;
  bf16x8 aR[8], bR[4];

#define STAGE_G2(T) { \
    int k0_ = (T) * BK; \
    unsigned short* dA = &sA[(T) & 1][0]; \
    unsigned short* dB = &sB[(T) & 1][0]; \
    _Pragma("unroll") for (int i = 0; i < 4; i++) { \
      int c = w * 4 + i; \
      int rA_ = row0 + 8 * c + srow8; rA_ = rA_ < T_PAD - 1 ? rA_ : T_PAD - 1; \
      gload16(act + (long)rA_ * H_DIM + k0_ + scol, (char*)dA + c * 1024 + lane * 16); \
      int rB_ = 8 * c + srow8; \
      gload16(Bb + (long)rB_ * H_DIM + k0_ + scol, (char*)dB + c * 1024 + lane * 16); \
    } }

  const int NT = H_DIM / BK;  // 64
  STAGE_G2(0);
  for (int t = 0; t < NT; ++t) {
    int cur = t & 1;
    if (t + 1 < NT) {
      STAGE_G2(t + 1);
      ITER_TOP(8)
    } else {
      ITER_TOP(0)
    }
    DSA(0); DSB(0); PHASE_PRE; MMA(0, 0); PHASE_POST;
    DSB(1);         PHASE_PRE; MMA(0, 1); PHASE_POST;
    DSA(1);         PHASE_PRE; MMA(1, 1); PHASE_POST;
    DSB(0);         PHASE_PRE; MMA(1, 0); PHASE_POST;
  }
#undef STAGE_G2

  int lr4 = q * 4;
#pragma unroll
  for (int mt = 0; mt < 8; mt++) {
#pragma unroll
    for (int j = 0; j < 4; j++) {
      f32x4 c4 = acc[mt][j];
      int f = n0 + wn * 64 + j * 16 + lrow;
      long mbase = row0 + wm * 128 + mt * 16 + lr4;
#pragma unroll
      for (int r = 0; r < 4; r++) {
        long m = mbase + r;
        if (m < row_end)
          eout[m * F_DIM + f] = f2bf(c4[r]);
      }
    }
  }
}

// ---------- 9. combine: out = w0*eout[p0] + w1*eout[p1] ----------
__global__ __launch_bounds__(256) void k_combine(const unsigned short* __restrict__ eout,
                                                 const int* __restrict__ meta_pos,
                                                 const float* __restrict__ meta_w,
                                                 float* __restrict__ out) {
  int t = blockIdx.x;
  int tid = threadIdx.x;
  int p0 = meta_pos[2 * t], p1 = meta_pos[2 * t + 1];
  float w0 = meta_w[2 * t], w1 = meta_w[2 * t + 1];
  const ushort4* r0 = (const ushort4*)(eout + (long)p0 * F_DIM);
  const ushort4* r1 = (const ushort4*)(eout + (long)p1 * F_DIM);
  float4* o = (float4*)(out + (long)t * F_DIM);
  for (int i = tid; i < F_DIM / 4; i += 256) {
    ushort4 a = r0[i], b = r1[i];
    float4 v;
    v.x = w0 * bf2f(a.x) + w1 * bf2f(b.x);
    v.y = w0 * bf2f(a.y) + w1 * bf2f(b.y);
    v.z = w0 * bf2f(a.z) + w1 * bf2f(b.z);
    v.w = w0 * bf2f(a.w) + w1 * bf2f(b.w);
    o[i] = v;
  }
}

// ---------- workspace layout (bytes) ----------
#define WG_OFF   0L
#define SX_OFF   268435456L
#define ACT_OFF  (268435456L + 67633152L)
#define CTRL_OFF (ACT_OFF + 135266304L)

extern "C" void kernel_launch(void* const* d_in, const int* in_sizes, int n_in,
                              void* d_out, int out_size, void* d_ws, size_t ws_size,
                              hipStream_t stream) {
  const float* x    = (const float*)d_in[0];
  const float* wr   = (const float*)d_in[1];
  const float* wgat = (const float*)d_in[2];
  const float* wlin = (const float*)d_in[3];
  const float* pes  = (const float*)d_in[4];
  const float* rsc  = (const float*)d_in[5];
  float* out = (float*)d_out;

  char* ws = (char*)d_ws;
  unsigned short* wg_bf = (unsigned short*)(ws + WG_OFF);
  unsigned short* wlt   = (unsigned short*)(ws + WG_OFF);   // reuse after GEMM1
  unsigned short* sx    = (unsigned short*)(ws + SX_OFF);
  unsigned short* eout  = (unsigned short*)(ws + SX_OFF);   // reuse after GEMM1
  unsigned short* act   = (unsigned short*)(ws + ACT_OFF);
  char* ctrl = ws + CTRL_OFF;
  int*   counts   = (int*)(ctrl + 0);
  int*   fills    = (int*)(ctrl + 32);
  int*   segoff   = (int*)(ctrl + 64);
  int*   nblocks  = (int*)(ctrl + 128);
  int4*  sched    = (int4*)(ctrl + 256);
  int*   meta_e   = (int*)(ctrl + 4096);
  int*   meta_pos = (int*)(ctrl + 4096 + 65536);
  float* meta_w   = (float*)(ctrl + 4096 + 131072);
  int*   tok_of_row = (int*)(ctrl + 4096 + 196608);

  hipMemsetAsync(ctrl, 0, 64, stream);  // counts + fills

  k_convert<<<16384, 256, 0, stream>>>(wgat, wg_bf, (long)E_NUM * 2 * H_DIM * F_DIM / 4);
  k_router<<<B_TOK, 256, 0, stream>>>(x, wr, rsc, pes, counts, meta_e, meta_w);
  k_sched<<<1, 64, 0, stream>>>(counts, segoff, nblocks, sched);
  k_scatter<<<B_TOK / 256, 256, 0, stream>>>(meta_e, segoff, fills, meta_pos, tok_of_row);
  k_gather<<<T_PAD, 256, 0, stream>>>(x, tok_of_row, sx);
  k_gemm_gate<<<dim3(2 * H_DIM / BN, NMB_MAX), 512, 0, stream>>>(sx, wg_bf, sched, nblocks, act);
  k_transpose<<<dim3(F_DIM / 64, H_DIM / 64, E_NUM), 256, 0, stream>>>(wlin, wlt);
  k_gemm_out<<<dim3(F_DIM / BN, NMB_MAX), 512, 0, stream>>>(act, wlt, sched, nblocks, eout);
  k_combine<<<B_TOK, 256, 0, stream>>>(eout, meta_pos, meta_w, out);
}

// Round 2
// 2609.042 us; speedup vs baseline: 1.0063x; 1.0063x over previous
//
#include <hip/hip_runtime.h>
#include <stdint.h>

#define F_DIM 2048
#define H_DIM 4096
#define E_NUM 8
#define B_TOK 8192    // G*S tokens
#define T_ROWS 16384  // B_TOK * top_k
#define T_PAD  16512  // +128 pad rows (stage loads clamp to T_PAD-1)
#define NMB_MAX 72    // max 256-row M-blocks (64 + 8 partials)
#define BK 64
#define BM 256
#define BN 256

typedef __attribute__((ext_vector_type(8))) short bf16x8;   // 8 bf16 (4 VGPRs)
typedef __attribute__((ext_vector_type(4))) float f32x4;    // 4 fp32 acc

// ---------- helpers ----------
__device__ __forceinline__ unsigned short f2bf(float f) {
  union { float f; unsigned u; } v; v.f = f;
  unsigned u = v.u;
  unsigned r = u + 0x7fffu + ((u >> 16) & 1u);   // RNE
  return (unsigned short)(r >> 16);
}
__device__ __forceinline__ float bf2f(unsigned short u) {
  union { unsigned u; float f; } v; v.u = ((unsigned)u) << 16;
  return v.f;
}
__device__ __forceinline__ float gelu_tanh(float x) {
  float z = 0.7978845608028654f * (x + 0.044715f * x * x * x);
  float t = 1.0f - 2.0f / (__expf(2.0f * z) + 1.0f);
  return 0.5f * x * (1.0f + t);
}
__device__ __forceinline__ void gload16(const void* g, void* l) {
  __builtin_amdgcn_global_load_lds(
      (const __attribute__((address_space(1))) void*)g,
      (__attribute__((address_space(3))) void*)l, 16, 0, 0);
}

// ---------- 1. fp32 -> bf16 elementwise (w_gating) ----------
__global__ __launch_bounds__(256) void k_convert(const float* __restrict__ src,
                                                 unsigned short* __restrict__ dst,
                                                 long n4) {
  long i = (long)blockIdx.x * blockDim.x + threadIdx.x;
  long stride = (long)gridDim.x * blockDim.x;
  for (; i < n4; i += stride) {
    float4 v = ((const float4*)src)[i];
    ushort4 o;
    o.x = f2bf(v.x); o.y = f2bf(v.y); o.z = f2bf(v.z); o.w = f2bf(v.w);
    ((ushort4*)dst)[i] = o;
  }
}

// ---------- 2. router: RMSnorm -> logits -> softmax top-2 ----------
__global__ __launch_bounds__(256) void k_router(const float* __restrict__ x,
                                                const float* __restrict__ wr,
                                                const float* __restrict__ rscale,
                                                const float* __restrict__ pes,
                                                int* __restrict__ counts,
                                                int* __restrict__ meta_e,
                                                float* __restrict__ meta_w) {
  int t = blockIdx.x;
  int tid = threadIdx.x;
  const float4* x4 = (const float4*)(x + (long)t * F_DIM);
  float4 v0 = x4[tid], v1 = x4[tid + 256];
  const float4* s4 = (const float4*)rscale;
  float4 s0 = s4[tid], s1 = s4[tid + 256];

  __shared__ float red[4];
  __shared__ float lg[4][8];

  float ss = v0.x * v0.x + v0.y * v0.y + v0.z * v0.z + v0.w * v0.w +
             v1.x * v1.x + v1.y * v1.y + v1.z * v1.z + v1.w * v1.w;
  for (int o = 32; o >= 1; o >>= 1) ss += __shfl_down(ss, o, 64);
  if ((tid & 63) == 0) red[tid >> 6] = ss;
  __syncthreads();
  float sumsq = red[0] + red[1] + red[2] + red[3];
  float scale = rsqrtf(sumsq * (1.0f / F_DIM) + 1e-6f) * rsqrtf((float)F_DIM);

  float acc[8];
#pragma unroll
  for (int e = 0; e < 8; e++) acc[e] = 0.f;
#pragma unroll
  for (int j = 0; j < 4; j++) {
    float u = ((const float*)&v0)[j] * ((const float*)&s0)[j];
    const float4* wrow = (const float4*)(wr + (long)(4 * tid + j) * 8);
    float4 wa = wrow[0], wb = wrow[1];
    acc[0] += u * wa.x; acc[1] += u * wa.y; acc[2] += u * wa.z; acc[3] += u * wa.w;
    acc[4] += u * wb.x; acc[5] += u * wb.y; acc[6] += u * wb.z; acc[7] += u * wb.w;
  }
#pragma unroll
  for (int j = 0; j < 4; j++) {
    float u = ((const float*)&v1)[j] * ((const float*)&s1)[j];
    const float4* wrow = (const float4*)(wr + (long)(4 * (tid + 256) + j) * 8);
    float4 wa = wrow[0], wb = wrow[1];
    acc[0] += u * wa.x; acc[1] += u * wa.y; acc[2] += u * wa.z; acc[3] += u * wa.w;
    acc[4] += u * wb.x; acc[5] += u * wb.y; acc[6] += u * wb.z; acc[7] += u * wb.w;
  }
#pragma unroll
  for (int e = 0; e < 8; e++) {
    float a = acc[e];
    for (int o = 32; o >= 1; o >>= 1) a += __shfl_down(a, o, 64);
    if ((tid & 63) == 0) lg[tid >> 6][e] = a;
  }
  __syncthreads();
  if (tid == 0) {
    float l[8];
#pragma unroll
    for (int e = 0; e < 8; e++)
      l[e] = (lg[0][e] + lg[1][e] + lg[2][e] + lg[3][e]) * scale;
    int e0 = 0;
    for (int e = 1; e < 8; e++) if (l[e] > l[e0]) e0 = e;
    int e1 = (e0 == 0) ? 1 : 0;
    for (int e = 0; e < 8; e++) if (e != e0 && l[e] > l[e1]) e1 = e;
    float p1 = __expf(l[e1] - l[e0]);
    float inv = 1.0f / (1.0f + p1);
    meta_e[2 * t] = e0; meta_e[2 * t + 1] = e1;
    meta_w[2 * t] = inv * pes[e0];
    meta_w[2 * t + 1] = p1 * inv * pes[e1];
    atomicAdd(&counts[e0], 1);
    atomicAdd(&counts[e1], 1);
  }
}

// ---------- 3. prefix sum + M-block schedule (256-row blocks) ----------
__global__ void k_sched(const int* __restrict__ counts, int* __restrict__ segoff,
                        int* __restrict__ nblocks, int4* __restrict__ sched) {
  if (threadIdx.x == 0 && blockIdx.x == 0) {
    int off = 0, nb = 0;
    for (int e = 0; e < 8; e++) {
      segoff[e] = off;
      int c = counts[e];
      int end = off + c;
      for (int i = 0; i < c; i += BM) {
        sched[nb].x = off + i; sched[nb].y = end; sched[nb].z = e; nb++;
      }
      off = end;
    }
    segoff[8] = off;
    *nblocks = nb;
    for (int b = nb; b < NMB_MAX; b++) { sched[b].x = 0; sched[b].y = 0; sched[b].z = 0; }
  }
}

// ---------- 4. scatter: assign sorted positions ----------
__global__ __launch_bounds__(256) void k_scatter(const int* __restrict__ meta_e,
                                                 const int* __restrict__ segoff,
                                                 int* __restrict__ fills,
                                                 int* __restrict__ meta_pos,
                                                 int* __restrict__ tok_of_row) {
  int t = blockIdx.x * blockDim.x + threadIdx.x;
  if (t >= B_TOK) return;
#pragma unroll
  for (int s = 0; s < 2; s++) {
    int e = meta_e[2 * t + s];
    int pos = segoff[e] + atomicAdd(&fills[e], 1);
    meta_pos[2 * t + s] = pos;
    tok_of_row[pos] = t;
  }
}

// ---------- 5. gather x rows -> bf16 sorted_x (+zero pad rows) ----------
__global__ __launch_bounds__(256) void k_gather(const float* __restrict__ x,
                                                const int* __restrict__ tok_of_row,
                                                unsigned short* __restrict__ sx) {
  int r = blockIdx.x;
  int tid = threadIdx.x;
  unsigned short* dst = sx + (long)r * F_DIM;
  if (r < T_ROWS) {
    const float4* src = (const float4*)(x + (long)tok_of_row[r] * F_DIM);
    for (int i = tid; i < F_DIM / 4; i += 256) {
      float4 v = src[i];
      ushort4 o;
      o.x = f2bf(v.x); o.y = f2bf(v.y); o.z = f2bf(v.z); o.w = f2bf(v.w);
      ((ushort4*)dst)[i] = o;
    }
  } else {
    ushort4 z = make_ushort4(0, 0, 0, 0);
    for (int i = tid; i < F_DIM / 4; i += 256) ((ushort4*)dst)[i] = z;
  }
}

// ================= 256x256 8-phase GEMM machinery =================
// LDS granule XOR-swizzle: 16B granule g of row r stored at position g^(r&7);
// stage pre-swizzles the global source so linear global_load_lds lands right.
// Per K-iter: iter-top {stage A(next), vmcnt(4), barrier}, then 4 phases
// (8 barriers total). B(next) staged after phase 1.  Fragments: bR0 kept
// live so phase 4 is pure MFMA (24 ds_read_b128/iter).  vmcnt never drains
// to 0 in the main loop (T4).

#define DSA(MH) \
  _Pragma("unroll") for (int mt = 0; mt < 4; mt++) \
  _Pragma("unroll") for (int ks = 0; ks < 2; ks++) { \
    int r_ = wm * 128 + (MH) * 64 + mt * 16 + lrow; \
    aR[mt * 2 + ks] = *(const bf16x8*)&sA[cur][r_ * BK + ((((ks << 2) + q) ^ (r_ & 7)) << 3)]; \
  }

#define DSB(DST, NH) \
  _Pragma("unroll") for (int nt = 0; nt < 2; nt++) \
  _Pragma("unroll") for (int ks = 0; ks < 2; ks++) { \
    int r_ = wn * 64 + (NH) * 32 + nt * 16 + lrow; \
    DST[nt * 2 + ks] = *(const bf16x8*)&sB[cur][r_ * BK + ((((ks << 2) + q) ^ (r_ & 7)) << 3)]; \
  }

#define MMA(MH, BR, NH) \
  _Pragma("unroll") for (int mt = 0; mt < 4; mt++) \
  _Pragma("unroll") for (int nt = 0; nt < 2; nt++) \
  _Pragma("unroll") for (int ks = 0; ks < 2; ks++) \
    acc[(MH) * 4 + mt][(NH) * 2 + nt] = __builtin_amdgcn_mfma_f32_16x16x32_bf16( \
        aR[mt * 2 + ks], BR[nt * 2 + ks], acc[(MH) * 4 + mt][(NH) * 2 + nt], 0, 0, 0);

#define PHASE_PRE \
  asm volatile("s_barrier" ::: "memory"); \
  asm volatile("s_waitcnt lgkmcnt(0)" ::: "memory"); \
  __builtin_amdgcn_sched_barrier(0); \
  __builtin_amdgcn_s_setprio(1);

#define PHASE_POST \
  __builtin_amdgcn_s_setprio(0); \
  __builtin_amdgcn_sched_barrier(0); \
  asm volatile("s_barrier" ::: "memory");

#define ITOP(VMC) \
  asm volatile("s_waitcnt vmcnt(" #VMC ")" ::: "memory"); \
  __builtin_amdgcn_sched_barrier(0); \
  asm volatile("s_barrier" ::: "memory"); \
  __builtin_amdgcn_sched_barrier(0);

// phase-1 middle (no extra open barrier; iter-top barrier covers it)
#define PH1_MID \
  asm volatile("s_waitcnt lgkmcnt(0)" ::: "memory"); \
  __builtin_amdgcn_sched_barrier(0); \
  __builtin_amdgcn_s_setprio(1);

// XCD-bijective remap (m204; nwg % 8 == 0 in both GEMM grids)
__device__ __forceinline__ int xcd_remap(int lin, int nwg) {
  return (lin & 7) * (nwg >> 3) + (lin >> 3);
}

// ---------- 6. GEMM1: sorted_x @ w_gate, fused gelu(g0)*g1 ----------
// grid = (x = M-block fast, y = 32 N-cols).  After the XCD remap each XCD
// owns a contiguous mb-run within ~4 N-cols: concurrent same-XCD blocks
// share the B-panel (L2-hit) and each A-panel's N-reuse stays in-XCD.
__global__ __launch_bounds__(512, 2) void k_gemm_gate(
    const unsigned short* __restrict__ sx,  // [T_PAD][F]
    const unsigned short* __restrict__ wg,  // [E][2H][F]  (B^T layout)
    const int4* __restrict__ sched, const int* __restrict__ nblocks,
    unsigned short* __restrict__ act)       // [T_PAD][H]
{
  int lin = blockIdx.y * gridDim.x + blockIdx.x;
  int logical = xcd_remap(lin, NMB_MAX * 32);
  int mb = logical % NMB_MAX;
  int nbk = logical / NMB_MAX;
  if (mb >= *nblocks) return;
  int4 sc = sched[mb];
  int row0 = sc.x, row_end = sc.y, e = sc.z;
  int h0 = nbk * 128;

  __shared__ __align__(16) unsigned short sA[2][BM * BK];  // 64 KiB
  __shared__ __align__(16) unsigned short sB[2][BM * BK];  // 64 KiB

  int tid = threadIdx.x, lane = tid & 63, w = tid >> 6;
  int wm = w >> 2, wn = w & 3;            // 2 (M) x 4 (N) waves
  int lrow = lane & 15, q = lane >> 4;
  int srow8 = lane >> 3;                  // row within 8-row chunk
  int scol = ((lane & 7) ^ srow8) << 3;   // swizzled global granule (elements)

  const unsigned short* B0 = wg + ((long)e * 2 * H_DIM + h0) * F_DIM;
  const unsigned short* B1 = wg + ((long)e * 2 * H_DIM + H_DIM + h0) * F_DIM;

  f32x4 acc[8][4];
  f32x4 z4 = {0.f, 0.f, 0.f, 0.f};
#pragma unroll
  for (int i_ = 0; i_ < 8; i_++)
#pragma unroll
    for (int j_ = 0; j_ < 4; j_++) acc[i_][j_] = z4;
  bf16x8 aR[8], bR0[4], bR1[4];

#define STAGE_A1(T) { \
    int k0_ = (T) * BK; \
    unsigned short* dA = &sA[(T) & 1][0]; \
    _Pragma("unroll") for (int i = 0; i < 4; i++) { \
      int c = w * 4 + i; \
      int rA_ = row0 + 8 * c + srow8; rA_ = rA_ < T_PAD - 1 ? rA_ : T_PAD - 1; \
      gload16(sx + (long)rA_ * F_DIM + k0_ + scol, (char*)dA + c * 1024); \
    } }
#define STAGE_B1(T) { \
    int k0_ = (T) * BK; \
    unsigned short* dB = &sB[(T) & 1][0]; \
    _Pragma("unroll") for (int i = 0; i < 4; i++) { \
      int c = w * 4 + i; \
      int rB_ = 8 * c + srow8; \
      const unsigned short* bb = (((c >> 1) & 1) ? B1 : B0); \
      int hr_ = ((rB_ >> 5) << 4) + (rB_ & 15); \
      gload16(bb + (long)hr_ * F_DIM + k0_ + scol, (char*)dB + c * 1024); \
    } }

  const int NT = F_DIM / BK;  // 32
  STAGE_A1(0); STAGE_B1(0);
  for (int t = 0; t < NT; ++t) {
    int cur = t & 1;
    if (t + 1 < NT) {
      STAGE_A1(t + 1);
      ITOP(4)
    } else {
      ITOP(0)
    }
    // phase 1
    DSA(0); DSB(bR0, 0);
    PH1_MID; MMA(0, bR0, 0); PHASE_POST;
    if (t + 1 < NT) STAGE_B1(t + 1);
    // phase 2
    DSB(bR1, 1); PHASE_PRE; MMA(0, bR1, 1); PHASE_POST;
    // phase 3
    DSA(1);      PHASE_PRE; MMA(1, bR1, 1); PHASE_POST;
    // phase 4 (pure MFMA, bR0 still live)
                 PHASE_PRE; MMA(1, bR0, 0); PHASE_POST;
  }
#undef STAGE_A1
#undef STAGE_B1

  int lr4 = q * 4;
#pragma unroll
  for (int mt = 0; mt < 8; mt++) {
#pragma unroll
    for (int hf = 0; hf < 2; hf++) {
      f32x4 g0 = acc[mt][hf * 2], g1 = acc[mt][hf * 2 + 1];
      int h = h0 + (wn * 2 + hf) * 16 + lrow;
      long mbase = row0 + wm * 128 + mt * 16 + lr4;
#pragma unroll
      for (int r = 0; r < 4; r++) {
        long m = mbase + r;
        if (m < row_end)
          act[m * H_DIM + h] = f2bf(gelu_tanh(g0[r]) * g1[r]);
      }
    }
  }
}

// ---------- 7. transpose w_linear (E,H,F) fp32 -> (E,F,H) bf16 ----------
__global__ __launch_bounds__(256) void k_transpose(const float* __restrict__ wl,
                                                   unsigned short* __restrict__ wlt) {
  __shared__ float t[64 * 65];
  int e = blockIdx.z;
  int h0 = blockIdx.y * 64, f0 = blockIdx.x * 64;
  int tx = threadIdx.x & 63, ty = threadIdx.x >> 6;  // (64,4)
  const float* src = wl + ((long)e * H_DIM + h0) * F_DIM + f0;
#pragma unroll
  for (int r = 0; r < 16; r++) {
    int hl = r * 4 + ty;
    t[hl * 65 + tx] = src[(long)hl * F_DIM + tx];
  }
  __syncthreads();
  unsigned short* dst = wlt + ((long)e * F_DIM + f0) * H_DIM + h0;
#pragma unroll
  for (int r = 0; r < 16; r++) {
    int fl = r * 4 + ty;
    dst[(long)fl * H_DIM + tx] = f2bf(t[tx * 65 + fl]);
  }
}

// ---------- 8. GEMM2: act @ w_linear^T -> eout ----------
// grid = (x = M-block fast, y = 8 N-cols); nbk-fast logical decomposition:
// each XCD owns 9 mb x all 8 nbk -> A-panel fetched by ONE xcd, B K-slices
// L2-shared across the 8 concurrent nbk of the same mb-group.
__global__ __launch_bounds__(512, 2) void k_gemm_out(
    const unsigned short* __restrict__ act,  // [T_PAD][H]
    const unsigned short* __restrict__ wlt,  // [E][F][H]  (B^T layout)
    const int4* __restrict__ sched, const int* __restrict__ nblocks,
    unsigned short* __restrict__ eout)       // [T_ROWS][F]
{
  int lin = blockIdx.y * gridDim.x + blockIdx.x;
  int logical = xcd_remap(lin, NMB_MAX * 8);
  int nbk = logical % 8;
  int mb = logical / 8;
  if (mb >= *nblocks) return;
  int4 sc = sched[mb];
  int row0 = sc.x, row_end = sc.y, e = sc.z;
  int n0 = nbk * BN;

  __shared__ __align__(16) unsigned short sA[2][BM * BK];
  __shared__ __align__(16) unsigned short sB[2][BM * BK];

  int tid = threadIdx.x, lane = tid & 63, w = tid >> 6;
  int wm = w >> 2, wn = w & 3;
  int lrow = lane & 15, q = lane >> 4;
  int srow8 = lane >> 3;
  int scol = ((lane & 7) ^ srow8) << 3;

  const unsigned short* Bb = wlt + ((long)e * F_DIM + n0) * H_DIM;

  f32x4 acc[8][4];
  f32x4 z4 = {0.f, 0.f, 0.f, 0.f};
#pragma unroll
  for (int i_ = 0; i_ < 8; i_++)
#pragma unroll
    for (int j_ = 0; j_ < 4; j_++) acc[i_][j_] = z4;
  bf16x8 aR[8], bR0[4], bR1[4];

#define STAGE_A2(T) { \
    int k0_ = (T) * BK; \
    unsigned short* dA = &sA[(T) & 1][0]; \
    _Pragma("unroll") for (int i = 0; i < 4; i++) { \
      int c = w * 4 + i; \
      int rA_ = row0 + 8 * c + srow8; rA_ = rA_ < T_PAD - 1 ? rA_ : T_PAD - 1; \
      gload16(act + (long)rA_ * H_DIM + k0_ + scol, (char*)dA + c * 1024); \
    } }
#define STAGE_B2(T) { \
    int k0_ = (T) * BK; \
    unsigned short* dB = &sB[(T) & 1][0]; \
    _Pragma("unroll") for (int i = 0; i < 4; i++) { \
      int c = w * 4 + i; \
      int rB_ = 8 * c + srow8; \
      gload16(Bb + (long)rB_ * H_DIM + k0_ + scol, (char*)dB + c * 1024); \
    } }

  const int NT = H_DIM / BK;  // 64
  STAGE_A2(0); STAGE_B2(0);
  for (int t = 0; t < NT; ++t) {
    int cur = t & 1;
    if (t + 1 < NT) {
      STAGE_A2(t + 1);
      ITOP(4)
    } else {
      ITOP(0)
    }
    // phase 1
    DSA(0); DSB(bR0, 0);
    PH1_MID; MMA(0, bR0, 0); PHASE_POST;
    if (t + 1 < NT) STAGE_B2(t + 1);
    // phase 2
    DSB(bR1, 1); PHASE_PRE; MMA(0, bR1, 1); PHASE_POST;
    // phase 3
    DSA(1);      PHASE_PRE; MMA(1, bR1, 1); PHASE_POST;
    // phase 4 (pure MFMA)
                 PHASE_PRE; MMA(1, bR0, 0); PHASE_POST;
  }
#undef STAGE_A2
#undef STAGE_B2

  int lr4 = q * 4;
#pragma unroll
  for (int mt = 0; mt < 8; mt++) {
#pragma unroll
    for (int j = 0; j < 4; j++) {
      f32x4 c4 = acc[mt][j];
      int f = n0 + wn * 64 + j * 16 + lrow;
      long mbase = row0 + wm * 128 + mt * 16 + lr4;
#pragma unroll
      for (int r = 0; r < 4; r++) {
        long m = mbase + r;
        if (m < row_end)
          eout[m * F_DIM + f] = f2bf(c4[r]);
      }
    }
  }
}

// ---------- 9. combine: out = w0*eout[p0] + w1*eout[p1] ----------
__global__ __launch_bounds__(256) void k_combine(const unsigned short* __restrict__ eout,
                                                 const int* __restrict__ meta_pos,
                                                 const float* __restrict__ meta_w,
                                                 float* __restrict__ out) {
  int t = blockIdx.x;
  int tid = threadIdx.x;
  int p0 = meta_pos[2 * t], p1 = meta_pos[2 * t + 1];
  float w0 = meta_w[2 * t], w1 = meta_w[2 * t + 1];
  const ushort4* r0 = (const ushort4*)(eout + (long)p0 * F_DIM);
  const ushort4* r1 = (const ushort4*)(eout + (long)p1 * F_DIM);
  float4* o = (float4*)(out + (long)t * F_DIM);
  for (int i = tid; i < F_DIM / 4; i += 256) {
    ushort4 a = r0[i], b = r1[i];
    float4 v;
    v.x = w0 * bf2f(a.x) + w1 * bf2f(b.x);
    v.y = w0 * bf2f(a.y) + w1 * bf2f(b.y);
    v.z = w0 * bf2f(a.z) + w1 * bf2f(b.z);
    v.w = w0 * bf2f(a.w) + w1 * bf2f(b.w);
    o[i] = v;
  }
}

// ---------- workspace layout (bytes) ----------
#define WG_OFF   0L
#define SX_OFF   268435456L
#define ACT_OFF  (268435456L + 67633152L)
#define CTRL_OFF (ACT_OFF + 135266304L)

extern "C" void kernel_launch(void* const* d_in, const int* in_sizes, int n_in,
                              void* d_out, int out_size, void* d_ws, size_t ws_size,
                              hipStream_t stream) {
  const float* x    = (const float*)d_in[0];
  const float* wr   = (const float*)d_in[1];
  const float* wgat = (const float*)d_in[2];
  const float* wlin = (const float*)d_in[3];
  const float* pes  = (const float*)d_in[4];
  const float* rsc  = (const float*)d_in[5];
  float* out = (float*)d_out;

  char* ws = (char*)d_ws;
  unsigned short* wg_bf = (unsigned short*)(ws + WG_OFF);
  unsigned short* wlt   = (unsigned short*)(ws + WG_OFF);   // reuse after GEMM1
  unsigned short* sx    = (unsigned short*)(ws + SX_OFF);
  unsigned short* eout  = (unsigned short*)(ws + SX_OFF);   // reuse after GEMM1
  unsigned short* act   = (unsigned short*)(ws + ACT_OFF);
  char* ctrl = ws + CTRL_OFF;
  int*   counts   = (int*)(ctrl + 0);
  int*   fills    = (int*)(ctrl + 32);
  int*   segoff   = (int*)(ctrl + 64);
  int*   nblocks  = (int*)(ctrl + 128);
  int4*  sched    = (int4*)(ctrl + 256);
  int*   meta_e   = (int*)(ctrl + 4096);
  int*   meta_pos = (int*)(ctrl + 4096 + 65536);
  float* meta_w   = (float*)(ctrl + 4096 + 131072);
  int*   tok_of_row = (int*)(ctrl + 4096 + 196608);

  hipMemsetAsync(ctrl, 0, 64, stream);  // counts + fills

  k_convert<<<16384, 256, 0, stream>>>(wgat, wg_bf, (long)E_NUM * 2 * H_DIM * F_DIM / 4);
  k_router<<<B_TOK, 256, 0, stream>>>(x, wr, rsc, pes, counts, meta_e, meta_w);
  k_sched<<<1, 64, 0, stream>>>(counts, segoff, nblocks, sched);
  k_scatter<<<B_TOK / 256, 256, 0, stream>>>(meta_e, segoff, fills, meta_pos, tok_of_row);
  k_gather<<<T_PAD, 256, 0, stream>>>(x, tok_of_row, sx);
  k_gemm_gate<<<dim3(NMB_MAX, 32), 512, 0, stream>>>(sx, wg_bf, sched, nblocks, act);
  k_transpose<<<dim3(F_DIM / 64, H_DIM / 64, E_NUM), 256, 0, stream>>>(wlin, wlt);
  k_gemm_out<<<dim3(NMB_MAX, 8), 512, 0, stream>>>(act, wlt, sched, nblocks, eout);
  k_combine<<<B_TOK, 256, 0, stream>>>(eout, meta_pos, meta_w, out);
}